// Round 14
// baseline (298.127 us; speedup 1.0000x reference)
//
#include <hip/hip_runtime.h>
#include <hip/hip_bf16.h>
#include <cstdint>

typedef __attribute__((ext_vector_type(8))) short bf16x8;
typedef __attribute__((ext_vector_type(4))) float f32x4;
typedef __attribute__((ext_vector_type(2))) unsigned int u32x2;

#define B_   16
#define C_   512
#define HW_  4096
#define M3_  384
#define HWP_ 1024
#define CV_  256

__device__ __forceinline__ unsigned short f2b(float f) {
  union { float f; unsigned u; } v; v.f = f;
  unsigned r = v.u + 0x7fffu + ((v.u >> 16) & 1u);   // RNE
  return (unsigned short)(r >> 16);
}
__device__ __forceinline__ float b2f(unsigned short b) {
  union { unsigned u; float f; } v; v.u = ((unsigned)b) << 16;
  return v.f;
}
__device__ __forceinline__ unsigned pkbf16(float a, float b) {
  // compiler emits v_cvt_pk_bf16_f32 (RNE), 2 floats per instruction
  __hip_bfloat162 h = __float22bfloat162_rn(make_float2(a, b));
  union { __hip_bfloat162 h; unsigned u; } cv; cv.h = h; return cv.u;
}
__device__ __forceinline__ f32x4 mfma16(bf16x8 a, bf16x8 b, f32x4 c) {
  return __builtin_amdgcn_mfma_f32_16x16x32_bf16(a, b, c, 0, 0, 0);
}
// async global->LDS, 16B per lane; LDS dest = wave-uniform base + lane*16
__device__ __forceinline__ void gload_lds16(const unsigned short* g, unsigned short* l) {
  __builtin_amdgcn_global_load_lds(
      (const __attribute__((address_space(1))) void*)g,
      (__attribute__((address_space(3))) void*)l, 16, 0, 0);
}

// ---------------------------------------------------------------- K0: x [b][c][n] f32 -> xb [b][n][c] bf16
__global__ __launch_bounds__(256) void k_transpose(const float* __restrict__ x,
                                                   unsigned short* __restrict__ xb) {
  __shared__ unsigned short t[64][66];
  const int b = blockIdx.z, k0 = blockIdx.y * 64, n0 = blockIdx.x * 64;
  const float* xp = x + (size_t)b * C_ * HW_;
  const int ln = threadIdx.x & 63, g = threadIdx.x >> 6;
  for (int kk = g; kk < 64; kk += 4)
    t[kk][ln] = f2b(xp[(size_t)(k0 + kk) * HW_ + n0 + ln]);
  __syncthreads();
  unsigned short* xo = xb + (size_t)b * HW_ * C_;
  for (int nn = g; nn < 64; nn += 4)
    xo[(size_t)(n0 + nn) * C_ + k0 + ln] = t[ln][nn];
}

// ---------------------------------------------------------------- K0b: transpose the 4 weight matrices (f32)
__global__ __launch_bounds__(256) void k_wtrans(
    const float* __restrict__ Wq, const float* __restrict__ Wk,
    const float* __restrict__ Wv, const float* __restrict__ Wo,
    float* __restrict__ wt) {
  const float* w; int out, in; float* dst;
  switch (blockIdx.z) {
    case 0: w = Wq; out = 64;  in = 512; dst = wt;          break;
    case 1: w = Wk; out = 64;  in = 512; dst = wt + 32768;  break;
    case 2: w = Wv; out = 256; in = 512; dst = wt + 65536;  break;
    default: w = Wo; out = 512; in = 256; dst = wt + 196608; break;
  }
  const int o0 = blockIdx.y * 64, i0 = blockIdx.x * 64;
  if (o0 >= out || i0 >= in) return;
  __shared__ float t[64][65];
  const int ln = threadIdx.x & 63, g = threadIdx.x >> 6;
  for (int oo = g; oo < 64; oo += 4)
    t[oo][ln] = w[(size_t)(o0 + oo) * in + i0 + ln];
  __syncthreads();
  for (int ii = g; ii < 64; ii += 4)
    dst[(size_t)(i0 + ii) * out + o0 + ln] = t[ln][ii];
}

// ---------------------------------------------------------------- K1: spectral norm, 1024 thr / matrix
__device__ __forceinline__ float breduce1024(float val, float* red) {
  __syncthreads();
#pragma unroll
  for (int off = 32; off > 0; off >>= 1) val += __shfl_down(val, off);
  if ((threadIdx.x & 63) == 0) red[threadIdx.x >> 6] = val;
  __syncthreads();
  float s = 0.f;
#pragma unroll
  for (int i = 0; i < 16; ++i) s += red[i];
  return s;
}

__global__ __launch_bounds__(1024) void k_specnorm(
    const float* __restrict__ Wq, const float* __restrict__ Wk,
    const float* __restrict__ Wv, const float* __restrict__ Wo,
    const float* __restrict__ wt,
    unsigned short* __restrict__ wqkv, unsigned short* __restrict__ wob) {
  __shared__ float u[512], v[512];
  __shared__ float part[4096];
  __shared__ float red[16];
  const float* w; const float* wT; int out, in; unsigned short* dst;
  switch (blockIdx.x) {
    case 0: w = Wq; wT = wt;          out = 64;  in = 512; dst = wqkv;             break;
    case 1: w = Wk; wT = wt + 32768;  out = 64;  in = 512; dst = wqkv + 64 * 512;  break;
    case 2: w = Wv; wT = wt + 65536;  out = 256; in = 512; dst = wqkv + 128 * 512; break;
    default: w = Wo; wT = wt + 196608; out = 512; in = 256; dst = wob;             break;
  }
  const int tid = threadIdx.x;
  const float rs = rsqrtf((float)out);
  if (tid < out) u[tid] = rs;
  __syncthreads();
  for (int it = 0; it < 5; ++it) {
    {
      const int G = in >> 2, nch = 1024 / G;
      const int ch = tid / G, grp = tid - ch * G;
      const int rpc = out / nch, obase = ch * rpc;
      f32x4 acc = {0.f, 0.f, 0.f, 0.f};
#pragma unroll 8
      for (int r = 0; r < rpc; ++r) {
        const int o = obase + r;
        const f32x4 wv = *reinterpret_cast<const f32x4*>(&w[(size_t)o * in + grp * 4]);
        const float uo = u[o];
        acc[0] += wv[0] * uo; acc[1] += wv[1] * uo;
        acc[2] += wv[2] * uo; acc[3] += wv[3] * uo;
      }
      *reinterpret_cast<f32x4*>(&part[ch * in + grp * 4]) = acc;
      __syncthreads();
      if (tid < in) {
        float s = 0.f;
        for (int c2 = 0; c2 < nch; ++c2) s += part[c2 * in + tid];
        v[tid] = s;
      }
    }
    {
      float ss = 0.f;
      __syncthreads();
      if (tid < in) ss = v[tid] * v[tid];
      ss = breduce1024(ss, red);
      const float sv = 1.f / (sqrtf(ss) + 1e-12f);
      if (tid < in) v[tid] *= sv;
      __syncthreads();
    }
    {
      const int G = out >> 2, nch = 1024 / G;
      const int ch = tid / G, grp = tid - ch * G;
      const int cpc = in / nch, cbase = ch * cpc;
      f32x4 acc = {0.f, 0.f, 0.f, 0.f};
#pragma unroll 8
      for (int r = 0; r < cpc; ++r) {
        const int c = cbase + r;
        const f32x4 wv = *reinterpret_cast<const f32x4*>(&wT[(size_t)c * out + grp * 4]);
        const float vc = v[c];
        acc[0] += wv[0] * vc; acc[1] += wv[1] * vc;
        acc[2] += wv[2] * vc; acc[3] += wv[3] * vc;
      }
      *reinterpret_cast<f32x4*>(&part[ch * out + grp * 4]) = acc;
      __syncthreads();
      if (tid < out) {
        float s = 0.f;
        for (int c2 = 0; c2 < nch; ++c2) s += part[c2 * out + tid];
        u[tid] = s;
      }
    }
    {
      float su = 0.f;
      __syncthreads();
      if (tid < out) su = u[tid] * u[tid];
      su = breduce1024(su, red);
      const float sv2 = 1.f / (sqrtf(su) + 1e-12f);
      if (tid < out) u[tid] *= sv2;
      __syncthreads();
    }
  }
  float sp = 0.f;
  {
    const int G = out >> 2, nch = 1024 / G;
    const int ch = tid / G, grp = tid - ch * G;
    const int cpc = in / nch, cbase = ch * cpc;
    f32x4 acc = {0.f, 0.f, 0.f, 0.f};
#pragma unroll 8
    for (int r = 0; r < cpc; ++r) {
      const int c = cbase + r;
      const f32x4 wv = *reinterpret_cast<const f32x4*>(&wT[(size_t)c * out + grp * 4]);
      const float vc = v[c];
      acc[0] += wv[0] * vc; acc[1] += wv[1] * vc;
      acc[2] += wv[2] * vc; acc[3] += wv[3] * vc;
    }
    *reinterpret_cast<f32x4*>(&part[ch * out + grp * 4]) = acc;
    __syncthreads();
    if (tid < out) {
      float s = 0.f;
      for (int c2 = 0; c2 < nch; ++c2) s += part[c2 * out + tid];
      sp = s * u[tid];
    }
  }
  sp = breduce1024(sp, red);
  const float oscale = (blockIdx.x == 0) ? 1.44269504f : 1.0f;
  const float inv_sigma = (1.f / sp) * oscale;
  const int total = out * in;
  for (int i = tid * 4; i < total; i += 4096) {
    const f32x4 wv = *reinterpret_cast<const f32x4*>(&w[i]);
    u32x2 pw;
    pw[0] = ((unsigned)f2b(wv[1] * inv_sigma) << 16) | f2b(wv[0] * inv_sigma);
    pw[1] = ((unsigned)f2b(wv[3] * inv_sigma) << 16) | f2b(wv[2] * inv_sigma);
    *reinterpret_cast<u32x2*>(&dst[i]) = pw;
  }
}

// ---------------------------------------------------------------- K2: Yt[b][n][m] = xb[b][n][k] * wqkv[m][k]
__global__ __launch_bounds__(256) void k_gemm_qkv(
    const unsigned short* __restrict__ xb, const unsigned short* __restrict__ wqkv,
    unsigned short* __restrict__ yt) {
  __shared__ alignas(16) char smem[32768];
  unsigned short* As = (unsigned short*)smem;
  unsigned short* Bs = (unsigned short*)(smem + 16384);
  const int lid = blockIdx.x;
  const int swz = (lid & 7) * 192 + (lid >> 3);
  const int mt = swz % 3, rest = swz / 3;
  const int nt = rest & 31, b = rest >> 5;
  const int n0 = nt * 128, m0 = mt * 128;
  const unsigned short* Ap = xb + (size_t)b * HW_ * C_ + (size_t)n0 * C_;
  const unsigned short* Bp = wqkv + (size_t)m0 * C_;
  const int tid = threadIdx.x, lane = tid & 63, wid = tid >> 6;
  const int wn = (wid >> 1) * 64, wm = (wid & 1) * 64;
  f32x4 acc[4][4] = {};
  for (int k0 = 0; k0 < C_; k0 += 64) {
    __syncthreads();
#pragma unroll
    for (int i = 0; i < 4; ++i) {
      const int r = i * 32 + (tid >> 3);
      const int s = tid & 7;
      const int rw = i * 32 + wid * 8;
      const size_t goff = (size_t)r * C_ + k0 + (size_t)((s ^ (r & 7)) * 8);
      gload_lds16(&Ap[goff], &As[rw * 64]);
      gload_lds16(&Bp[goff], &Bs[rw * 64]);
    }
    __syncthreads();
#pragma unroll
    for (int kk = 0; kk < 2; ++kk) {
      bf16x8 af[4], bfr[4];
#pragma unroll
      for (int i = 0; i < 4; ++i) {
        const int r = wn + i * 16 + (lane & 15);
        const int slot = (kk * 4 + (lane >> 4)) ^ (r & 7);
        af[i] = *reinterpret_cast<const bf16x8*>(&As[r * 64 + slot * 8]);
      }
#pragma unroll
      for (int j = 0; j < 4; ++j) {
        const int r = wm + j * 16 + (lane & 15);
        const int slot = (kk * 4 + (lane >> 4)) ^ (r & 7);
        bfr[j] = *reinterpret_cast<const bf16x8*>(&Bs[r * 64 + slot * 8]);
      }
#pragma unroll
      for (int i = 0; i < 4; ++i)
#pragma unroll
        for (int j = 0; j < 4; ++j) acc[i][j] = mfma16(af[i], bfr[j], acc[i][j]);
    }
  }
  unsigned short* eps = (unsigned short*)smem;
  unsigned short* Y = yt + (size_t)b * HW_ * M3_;
#pragma unroll
  for (int h = 0; h < 2; ++h) {
    __syncthreads();
    if ((wid >> 1) == h) {
#pragma unroll
      for (int i = 0; i < 4; ++i)
#pragma unroll
        for (int j = 0; j < 4; ++j)
#pragma unroll
          for (int r = 0; r < 4; ++r) {
            const int nl = i * 16 + (lane >> 4) * 4 + r;
            const int ml = wm + j * 16 + (lane & 15);
            eps[nl * 136 + ml] = f2b(acc[i][j][r]);
          }
    }
    __syncthreads();
#pragma unroll
    for (int t = 0; t < 4; ++t) {
      const int row = t * 16 + (tid >> 4);
      const int m8 = (tid & 15) * 8;
      *reinterpret_cast<f32x4*>(&Y[(size_t)(n0 + h * 64 + row) * M3_ + m0 + m8]) =
          *reinterpret_cast<const f32x4*>(&eps[row * 136 + m8]);
    }
  }
}

// ---------------------------------------------------------------- K3a: gt[b][mp][c] = maxpool(Yt cols 64..127)
__global__ __launch_bounds__(256) void k_pool_g(const unsigned short* __restrict__ yt,
                                                unsigned short* __restrict__ gt) {
  const int b = blockIdx.y, mp0 = blockIdx.x * 64;
  const int c = threadIdx.x & 63, dm = threadIdx.x >> 6;
  const unsigned short* Y = yt + (size_t)b * HW_ * M3_;
  unsigned short* G = gt + (size_t)b * HWP_ * 64;
  for (int mm = dm; mm < 64; mm += 4) {
    const int mp = mp0 + mm;
    const int n00 = (mp >> 5) * 128 + (mp & 31) * 2;
    const float a0 = b2f(Y[(size_t)n00 * M3_ + 64 + c]);
    const float a1 = b2f(Y[(size_t)(n00 + 1) * M3_ + 64 + c]);
    const float a2 = b2f(Y[(size_t)(n00 + 64) * M3_ + 64 + c]);
    const float a3 = b2f(Y[(size_t)(n00 + 65) * M3_ + 64 + c]);
    G[(size_t)mp * 64 + c] = f2b(fmaxf(fmaxf(a0, a1), fmaxf(a2, a3)));
  }
}

// ---------------------------------------------------------------- K3b: vt[b][cv][mp] = maxpool(Yt cols 128..383)^T
__global__ __launch_bounds__(256) void k_pool_vt(const unsigned short* __restrict__ yt,
                                                 unsigned short* __restrict__ vt) {
  __shared__ unsigned short t[64][66];
  const int b = blockIdx.z, mp0 = blockIdx.x * 64, cv0 = blockIdx.y * 64;
  const unsigned short* Y = yt + (size_t)b * HW_ * M3_;
  const int c = threadIdx.x & 63, dm = threadIdx.x >> 6;
  for (int mm = dm; mm < 64; mm += 4) {
    const int mp = mp0 + mm;
    const int n00 = (mp >> 5) * 128 + (mp & 31) * 2;
    const float a0 = b2f(Y[(size_t)n00 * M3_ + 128 + cv0 + c]);
    const float a1 = b2f(Y[(size_t)(n00 + 1) * M3_ + 128 + cv0 + c]);
    const float a2 = b2f(Y[(size_t)(n00 + 64) * M3_ + 128 + cv0 + c]);
    const float a3 = b2f(Y[(size_t)(n00 + 65) * M3_ + 128 + cv0 + c]);
    t[mm][c] = f2b(fmaxf(fmaxf(a0, a1), fmaxf(a2, a3)));
  }
  __syncthreads();
  unsigned short* V = vt + (size_t)b * CV_ * HWP_;
  for (int cc = dm; cc < 64; cc += 4)
    V[(size_t)(cv0 + cc) * HWP_ + mp0 + c] = t[c][cc];
}

// ---------------------------------------------------------------- K4: flash attention, 8 waves x 16q = 128q/block
// R13 single-barrier dbuf pipeline + VALU diet: v_cvt_pk P packing, pointer-
// increment prefetch addressing, deferred l-reduction, unroll-2 (static cur).
__global__ __launch_bounds__(512, 4) void k_attn(
    const unsigned short* __restrict__ yt, const unsigned short* __restrict__ gt,
    const unsigned short* __restrict__ vt, unsigned short* __restrict__ oat) {
  __shared__ alignas(16) char smem[59392];
  // Ks dbuf 2x[32kv][64ch] 4KB @0; Vs dbuf 2x[256cv][40sh] 20KB @8192
  // Ps 8 waves x [16q][40sh] 1.25KB @49152; epilogue eps 64x264 bf16 @0
  const int lid = blockIdx.x;                              // 512 blocks
  const int swz = (lid & 7) * 64 + (lid >> 3);
  const int q0 = (swz & 31) * 128, b = swz >> 5;
  const int tid = threadIdx.x, lane = tid & 63, wid = tid >> 6;  // 8 waves
  const int q = lane & 15, g = lane >> 4;
  const unsigned short* Qg = yt + (size_t)b * HW_ * M3_ + (size_t)(q0 + wid * 16) * M3_;
  const unsigned short* Gg = gt + (size_t)b * HWP_ * 64;
  const unsigned short* Vg = vt + (size_t)b * CV_ * HWP_;
  unsigned short* P = (unsigned short*)(smem + 49152) + wid * 640;  // 16q x 40sh
  // Q fragments (wave's 16 q rows), kept all kernel
  bf16x8 qf[2];
#pragma unroll
  for (int kk = 0; kk < 2; ++kk)
    qf[kk] = *reinterpret_cast<const bf16x8*>(&Qg[(size_t)q * M3_ + kk * 32 + g * 8]);
  // staging: K 256 chunks (tid<256), V 1024 chunks (2/thread)
  const int kr = tid >> 3, ks = tid & 7;   // valid when tid<256
  f32x4 kreg, vreg[2];
  // prologue: tile 0 -> regs -> buf0; tile 1 -> regs
  if (tid < 256) kreg = *reinterpret_cast<const f32x4*>(&Gg[(size_t)kr * 64 + ks * 8]);
  const unsigned short* vp0;
  const unsigned short* vp1;
  {
    const int i0c = tid, r0 = i0c >> 2, s0 = i0c & 3;
    const int i1c = tid + 512, r1 = i1c >> 2, s1 = i1c & 3;
    vp0 = Vg + (size_t)r0 * HWP_ + s0 * 8;
    vp1 = Vg + (size_t)r1 * HWP_ + s1 * 8;
    vreg[0] = *reinterpret_cast<const f32x4*>(vp0);
    vreg[1] = *reinterpret_cast<const f32x4*>(vp1);
  }
  {
    unsigned short* Kb = (unsigned short*)smem;
    unsigned short* Vb = (unsigned short*)(smem + 8192);
    if (tid < 256)
      *reinterpret_cast<f32x4*>(&Kb[kr * 64 + (ks ^ (kr & 7)) * 8]) = kreg;
    const int i0c = tid, r0 = i0c >> 2, s0 = i0c & 3;
    const int i1c = tid + 512, r1 = i1c >> 2, s1 = i1c & 3;
    *reinterpret_cast<f32x4*>(&Vb[r0 * 40 + s0 * 8]) = vreg[0];
    *reinterpret_cast<f32x4*>(&Vb[r1 * 40 + s1 * 8]) = vreg[1];
  }
  const unsigned short* kp = Gg + (size_t)(32 + kr) * 64 + ks * 8;  // tile 1 base
  if (tid < 256) kreg = *reinterpret_cast<const f32x4*>(kp);
  kp += 2048;                     // -> tile 2
  vp0 += 32; vp1 += 32;           // -> tile 1
  vreg[0] = *reinterpret_cast<const f32x4*>(vp0);
  vreg[1] = *reinterpret_cast<const f32x4*>(vp1);
  vp0 += 32; vp1 += 32;           // -> tile 2
  __syncthreads();
  f32x4 oacc[16] = {};
  float m_run = -1e30f, l_part = 0.f;
#pragma unroll 2
  for (int it = 0; it < 32; ++it) {
    const int cur = it & 1;
    unsigned short* Kc = (unsigned short*)(smem + cur * 4096);
    unsigned short* Vc = (unsigned short*)(smem + 8192 + cur * 20480);
    // stage tile it+1 into the other buffer (overlaps compute below)
    if (it < 31) {
      unsigned short* Kn = (unsigned short*)(smem + (cur ^ 1) * 4096);
      unsigned short* Vn = (unsigned short*)(smem + 8192 + (cur ^ 1) * 20480);
      if (tid < 256)
        *reinterpret_cast<f32x4*>(&Kn[kr * 64 + (ks ^ (kr & 7)) * 8]) = kreg;
      const int i0c = tid, r0 = i0c >> 2, s0 = i0c & 3;
      const int i1c = tid + 512, r1 = i1c >> 2, s1 = i1c & 3;
      *reinterpret_cast<f32x4*>(&Vn[r0 * 40 + s0 * 8]) = vreg[0];
      *reinterpret_cast<f32x4*>(&Vn[r1 * 40 + s1 * 8]) = vreg[1];
    }
    // issue loads for tile it+2 (pointer-increment addressing)
    if (it < 30) {
      if (tid < 256) kreg = *reinterpret_cast<const f32x4*>(kp);
      kp += 2048;
      vreg[0] = *reinterpret_cast<const f32x4*>(vp0);
      vreg[1] = *reinterpret_cast<const f32x4*>(vp1);
      vp0 += 32; vp1 += 32;
    }
    // QK^T (swapped): sacc rows kv(32), col q (wave's 16 q)
    f32x4 sacc[2] = {};
#pragma unroll
    for (int kk = 0; kk < 2; ++kk) {
      bf16x8 kf[2];
#pragma unroll
      for (int i = 0; i < 2; ++i) {
        const int row = i * 16 + q;
        const int sl = (kk * 4 + g) ^ (row & 7);
        kf[i] = *reinterpret_cast<const bf16x8*>(&Kc[row * 64 + sl * 8]);
      }
#pragma unroll
      for (int i = 0; i < 2; ++i) sacc[i] = mfma16(kf[i], qf[kk], sacc[i]);
    }
    // online softmax (log2 domain, defer-max, per-wave)
    float tmax = fmaxf(fmaxf(fmaxf(sacc[0][0], sacc[0][1]), fmaxf(sacc[0][2], sacc[0][3])),
                       fmaxf(fmaxf(sacc[1][0], sacc[1][1]), fmaxf(sacc[1][2], sacc[1][3])));
    tmax = fmaxf(tmax, __shfl_xor(tmax, 16));
    tmax = fmaxf(tmax, __shfl_xor(tmax, 32));
    if (__any(tmax > m_run + 11.0f)) {
      const float mnew = fmaxf(m_run, tmax);
      const float alpha = exp2f(m_run - mnew);
      m_run = mnew;
      l_part *= alpha;
      float al[4];
#pragma unroll
      for (int r = 0; r < 4; ++r) al[r] = __shfl(alpha, g * 4 + r);
#pragma unroll
      for (int j = 0; j < 16; ++j) {
        oacc[j][0] *= al[0]; oacc[j][1] *= al[1];
        oacc[j][2] *= al[2]; oacc[j][3] *= al[3];
      }
    }
#pragma unroll
    for (int i = 0; i < 2; ++i) {
      const float p0 = exp2f(sacc[i][0] - m_run);
      const float p1 = exp2f(sacc[i][1] - m_run);
      const float p2 = exp2f(sacc[i][2] - m_run);
      const float p3 = exp2f(sacc[i][3] - m_run);
      l_part += (p0 + p1) + (p2 + p3);
      u32x2 pw;
      pw[0] = pkbf16(p0, p1);
      pw[1] = pkbf16(p2, p3);
      *reinterpret_cast<u32x2*>(&P[q * 40 + i * 16 + g * 4]) = pw;
    }
    // PV: pa from wave-private P (k-slice g*8); vf from shared staged V
    __builtin_amdgcn_s_setprio(1);
    const bf16x8 pa = *reinterpret_cast<const bf16x8*>(&P[q * 40 + g * 8]);
#pragma unroll
    for (int j = 0; j < 16; ++j) {
      const int row = j * 16 + q;
      const bf16x8 vf = *reinterpret_cast<const bf16x8*>(&Vc[row * 40 + g * 8]);
      oacc[j] = mfma16(pa, vf, oacc[j]);
    }
    __builtin_amdgcn_s_setprio(0);
    __syncthreads();   // single barrier per tile
  }
  // epilogue: reduce l across groups (deferred), normalize, repack, store
  float lsum = l_part;
  lsum += __shfl_xor(lsum, 16);
  lsum += __shfl_xor(lsum, 32);
  float linv[4];
  {
    const float myinv = 1.f / lsum;
#pragma unroll
    for (int r = 0; r < 4; ++r) linv[r] = __shfl(myinv, g * 4 + r);
  }
  unsigned short* eps = (unsigned short*)smem;   // 64 x 264 bf16 = 33792B
  unsigned short* O = oat + (size_t)b * HW_ * CV_ + (size_t)q0 * CV_;
#pragma unroll
  for (int ch = 0; ch < 2; ++ch) {
    __syncthreads();
    if ((wid >> 2) == ch) {
#pragma unroll
      for (int j = 0; j < 16; ++j)
#pragma unroll
        for (int r = 0; r < 4; ++r) {
          const int row = (wid & 3) * 16 + g * 4 + r;
          const int cv = j * 16 + q;
          eps[row * 264 + cv] = f2b(oacc[j][r] * linv[r]);
        }
    }
    __syncthreads();
#pragma unroll
    for (int t = 0; t < 4; ++t) {
      const int row = t * 16 + (tid >> 5);
      const int cv8 = (tid & 31) * 8;
      *reinterpret_cast<f32x4*>(&O[(size_t)(ch * 64 + row) * CV_ + cv8]) =
          *reinterpret_cast<const f32x4*>(&eps[row * 264 + cv8]);
    }
  }
}

// ---------------------------------------------------------------- K5: out[b][co][n] = gamma * wo@Oatt^T + x
__global__ __launch_bounds__(256) void k_gemm_out(
    const unsigned short* __restrict__ oat, const unsigned short* __restrict__ wob,
    const float* __restrict__ x, const float* __restrict__ gamma,
    float* __restrict__ out) {
  __shared__ alignas(16) char smem[32768];
  unsigned short* As = (unsigned short*)smem;
  unsigned short* Bs = (unsigned short*)(smem + 16384);
  const int lid = blockIdx.x;
  const int swz = (lid & 7) * 256 + (lid >> 3);
  const int ct = swz & 3, nt = (swz >> 2) & 31, b = swz >> 7;
  const int n0 = nt * 128, co0 = ct * 128;
  const unsigned short* Ap = wob + (size_t)co0 * CV_;
  const unsigned short* Bp = oat + (size_t)b * HW_ * CV_ + (size_t)n0 * CV_;
  const int tid = threadIdx.x, lane = tid & 63, wid = tid >> 6;
  const int wc = (wid >> 1) * 64, wn = (wid & 1) * 64;
  f32x4 acc[4][4] = {};
  for (int k0 = 0; k0 < CV_; k0 += 64) {
    __syncthreads();
#pragma unroll
    for (int i = 0; i < 4; ++i) {
      const int r = i * 32 + (tid >> 3);
      const int s = tid & 7;
      const int rw = i * 32 + wid * 8;
      const size_t goff = (size_t)r * CV_ + k0 + (size_t)((s ^ (r & 7)) * 8);
      gload_lds16(&Ap[goff], &As[rw * 64]);
      gload_lds16(&Bp[goff], &Bs[rw * 64]);
    }
    __syncthreads();
#pragma unroll
    for (int kk = 0; kk < 2; ++kk) {
      bf16x8 af[4], bfr[4];
#pragma unroll
      for (int i = 0; i < 4; ++i) {
        const int r = wc + i * 16 + (lane & 15);
        const int slot = (kk * 4 + (lane >> 4)) ^ (r & 7);
        af[i] = *reinterpret_cast<const bf16x8*>(&As[r * 64 + slot * 8]);
      }
#pragma unroll
      for (int j = 0; j < 4; ++j) {
        const int r = wn + j * 16 + (lane & 15);
        const int slot = (kk * 4 + (lane >> 4)) ^ (r & 7);
        bfr[j] = *reinterpret_cast<const bf16x8*>(&Bs[r * 64 + slot * 8]);
      }
#pragma unroll
      for (int i = 0; i < 4; ++i)
#pragma unroll
        for (int j = 0; j < 4; ++j) acc[i][j] = mfma16(af[i], bfr[j], acc[i][j]);
    }
  }
  float* eps = (float*)smem;
  const float g = gamma[0];
  const size_t base = (size_t)b * C_ * HW_;
#pragma unroll
  for (int h = 0; h < 4; ++h) {
    __syncthreads();
    if ((wid >> 1) == (h >> 1)) {
#pragma unroll
      for (int ii = 0; ii < 2; ++ii) {
        const int i = (h & 1) * 2 + ii;
#pragma unroll
        for (int j = 0; j < 4; ++j)
#pragma unroll
          for (int r = 0; r < 4; ++r) {
            const int col2 = ii * 16 + (lane >> 4) * 4 + r;
            const int nl = wn + j * 16 + (lane & 15);
            eps[col2 * 132 + nl] = acc[i][j][r];
          }
      }
    }
    __syncthreads();
#pragma unroll
    for (int t = 0; t < 4; ++t) {
      const int row = t * 8 + (tid >> 5);
      const int col = (tid & 31) * 4;
      const size_t goff = base + (size_t)(co0 + h * 32 + row) * HW_ + n0 + col;
      const f32x4 xv = *reinterpret_cast<const f32x4*>(&x[goff]);
      const f32x4 av = *reinterpret_cast<const f32x4*>(&eps[row * 132 + col]);
      f32x4 ov;
      ov[0] = g * av[0] + xv[0];
      ov[1] = g * av[1] + xv[1];
      ov[2] = g * av[2] + xv[2];
      ov[3] = g * av[3] + xv[3];
      *reinterpret_cast<f32x4*>(&out[goff]) = ov;
    }
  }
}

// ---------------------------------------------------------------- launcher
extern "C" void kernel_launch(void* const* d_in, const int* in_sizes, int n_in,
                              void* d_out, int out_size, void* d_ws, size_t ws_size,
                              hipStream_t stream) {
  (void)in_sizes; (void)n_in; (void)out_size; (void)ws_size;
  const float* x     = (const float*)d_in[0];
  const float* Wq    = (const float*)d_in[1];
  const float* Wk    = (const float*)d_in[2];
  const float* Wv    = (const float*)d_in[3];
  const float* Wo    = (const float*)d_in[4];
  const float* gamma = (const float*)d_in[5];
  float* out = (float*)d_out;
  char* ws = (char*)d_ws;

  unsigned short* wqkv = (unsigned short*)(ws);                 // 384*512*2
  unsigned short* wob  = (unsigned short*)(ws + 393216);        // 512*256*2
  unsigned short* xb   = (unsigned short*)(ws + 655360);        // 64MB
  unsigned short* yt   = (unsigned short*)(ws + 67764224);      // 48MB
  unsigned short* gt   = (unsigned short*)(ws + 118095872);     // 2MB
  unsigned short* vt   = (unsigned short*)(ws + 120193024);     // 8MB
  unsigned short* oat  = xb;   // alias: xb dead after k_gemm_qkv
  float* wt = (float*)yt;      // alias: wT only live during specnorm (yt written later)

  k_transpose<<<dim3(64, 8, 16), 256, 0, stream>>>(x, xb);
  k_wtrans<<<dim3(8, 8, 4), 256, 0, stream>>>(Wq, Wk, Wv, Wo, wt);
  k_specnorm<<<4, 1024, 0, stream>>>(Wq, Wk, Wv, Wo, wt, wqkv, wob);
  k_gemm_qkv<<<1536, 256, 0, stream>>>(xb, wqkv, yt);
  k_pool_g<<<dim3(16, 16), 256, 0, stream>>>(yt, gt);
  k_pool_vt<<<dim3(16, 4, 16), 256, 0, stream>>>(yt, vt);
  k_attn<<<512, 512, 0, stream>>>(yt, gt, vt, oat);
  k_gemm_out<<<2048, 256, 0, stream>>>(oat, wob, x, gamma, out);
}

// Round 15
// 281.255 us; speedup vs baseline: 1.0600x; 1.0600x over previous
//
#include <hip/hip_runtime.h>
#include <hip/hip_bf16.h>
#include <cstdint>

typedef __attribute__((ext_vector_type(8))) short bf16x8;
typedef __attribute__((ext_vector_type(4))) float f32x4;
typedef __attribute__((ext_vector_type(2))) unsigned int u32x2;
typedef __attribute__((ext_vector_type(4))) unsigned int u32x4;

#define B_   16
#define C_   512
#define HW_  4096
#define M3_  384
#define HWP_ 1024
#define CV_  256

__device__ __forceinline__ unsigned short f2b(float f) {
  union { float f; unsigned u; } v; v.f = f;
  unsigned r = v.u + 0x7fffu + ((v.u >> 16) & 1u);   // RNE
  return (unsigned short)(r >> 16);
}
__device__ __forceinline__ float b2f(unsigned short b) {
  union { unsigned u; float f; } v; v.u = ((unsigned)b) << 16;
  return v.f;
}
__device__ __forceinline__ unsigned pkbf16(float a, float b) {
  __hip_bfloat162 h = __float22bfloat162_rn(make_float2(a, b));
  union { __hip_bfloat162 h; unsigned u; } cv; cv.h = h; return cv.u;
}
__device__ __forceinline__ f32x4 mfma16(bf16x8 a, bf16x8 b, f32x4 c) {
  return __builtin_amdgcn_mfma_f32_16x16x32_bf16(a, b, c, 0, 0, 0);
}
// async global->LDS, 16B per lane; LDS dest = wave-uniform base + lane*16
__device__ __forceinline__ void gload_lds16(const unsigned short* g, unsigned short* l) {
  __builtin_amdgcn_global_load_lds(
      (const __attribute__((address_space(1))) void*)g,
      (__attribute__((address_space(3))) void*)l, 16, 0, 0);
}

// ---------------------------------------------------------------- K0: x [b][c][n] f32 -> xb [b][n][c] bf16
__global__ __launch_bounds__(256) void k_transpose(const float* __restrict__ x,
                                                   unsigned short* __restrict__ xb) {
  __shared__ unsigned short t[64][66];
  const int b = blockIdx.z, k0 = blockIdx.y * 64, n0 = blockIdx.x * 64;
  const float* xp = x + (size_t)b * C_ * HW_;
  const int ln = threadIdx.x & 63, g = threadIdx.x >> 6;
  for (int kk = g; kk < 64; kk += 4)
    t[kk][ln] = f2b(xp[(size_t)(k0 + kk) * HW_ + n0 + ln]);
  __syncthreads();
  unsigned short* xo = xb + (size_t)b * HW_ * C_;
  for (int nn = g; nn < 64; nn += 4)
    xo[(size_t)(n0 + nn) * C_ + k0 + ln] = t[ln][nn];
}

// ---------------------------------------------------------------- K0b: transpose the 4 weight matrices (f32)
__global__ __launch_bounds__(256) void k_wtrans(
    const float* __restrict__ Wq, const float* __restrict__ Wk,
    const float* __restrict__ Wv, const float* __restrict__ Wo,
    float* __restrict__ wt) {
  const float* w; int out, in; float* dst;
  switch (blockIdx.z) {
    case 0: w = Wq; out = 64;  in = 512; dst = wt;          break;
    case 1: w = Wk; out = 64;  in = 512; dst = wt + 32768;  break;
    case 2: w = Wv; out = 256; in = 512; dst = wt + 65536;  break;
    default: w = Wo; out = 512; in = 256; dst = wt + 196608; break;
  }
  const int o0 = blockIdx.y * 64, i0 = blockIdx.x * 64;
  if (o0 >= out || i0 >= in) return;
  __shared__ float t[64][65];
  const int ln = threadIdx.x & 63, g = threadIdx.x >> 6;
  for (int oo = g; oo < 64; oo += 4)
    t[oo][ln] = w[(size_t)(o0 + oo) * in + i0 + ln];
  __syncthreads();
  for (int ii = g; ii < 64; ii += 4)
    dst[(size_t)(i0 + ii) * out + o0 + ln] = t[ln][ii];
}

// ---------------------------------------------------------------- K1: spectral norm, 1024 thr / matrix
__device__ __forceinline__ float breduce1024(float val, float* red) {
  __syncthreads();
#pragma unroll
  for (int off = 32; off > 0; off >>= 1) val += __shfl_down(val, off);
  if ((threadIdx.x & 63) == 0) red[threadIdx.x >> 6] = val;
  __syncthreads();
  float s = 0.f;
#pragma unroll
  for (int i = 0; i < 16; ++i) s += red[i];
  return s;
}

__global__ __launch_bounds__(1024) void k_specnorm(
    const float* __restrict__ Wq, const float* __restrict__ Wk,
    const float* __restrict__ Wv, const float* __restrict__ Wo,
    const float* __restrict__ wt,
    unsigned short* __restrict__ wqkv, unsigned short* __restrict__ wob) {
  __shared__ float u[512], v[512];
  __shared__ float part[4096];
  __shared__ float red[16];
  const float* w; const float* wT; int out, in; unsigned short* dst;
  switch (blockIdx.x) {
    case 0: w = Wq; wT = wt;          out = 64;  in = 512; dst = wqkv;             break;
    case 1: w = Wk; wT = wt + 32768;  out = 64;  in = 512; dst = wqkv + 64 * 512;  break;
    case 2: w = Wv; wT = wt + 65536;  out = 256; in = 512; dst = wqkv + 128 * 512; break;
    default: w = Wo; wT = wt + 196608; out = 512; in = 256; dst = wob;             break;
  }
  const int tid = threadIdx.x;
  const float rs = rsqrtf((float)out);
  if (tid < out) u[tid] = rs;
  __syncthreads();
  for (int it = 0; it < 5; ++it) {
    {
      const int G = in >> 2, nch = 1024 / G;
      const int ch = tid / G, grp = tid - ch * G;
      const int rpc = out / nch, obase = ch * rpc;
      f32x4 acc = {0.f, 0.f, 0.f, 0.f};
#pragma unroll 8
      for (int r = 0; r < rpc; ++r) {
        const int o = obase + r;
        const f32x4 wv = *reinterpret_cast<const f32x4*>(&w[(size_t)o * in + grp * 4]);
        const float uo = u[o];
        acc[0] += wv[0] * uo; acc[1] += wv[1] * uo;
        acc[2] += wv[2] * uo; acc[3] += wv[3] * uo;
      }
      *reinterpret_cast<f32x4*>(&part[ch * in + grp * 4]) = acc;
      __syncthreads();
      if (tid < in) {
        float s = 0.f;
        for (int c2 = 0; c2 < nch; ++c2) s += part[c2 * in + tid];
        v[tid] = s;
      }
    }
    {
      float ss = 0.f;
      __syncthreads();
      if (tid < in) ss = v[tid] * v[tid];
      ss = breduce1024(ss, red);
      const float sv = 1.f / (sqrtf(ss) + 1e-12f);
      if (tid < in) v[tid] *= sv;
      __syncthreads();
    }
    {
      const int G = out >> 2, nch = 1024 / G;
      const int ch = tid / G, grp = tid - ch * G;
      const int cpc = in / nch, cbase = ch * cpc;
      f32x4 acc = {0.f, 0.f, 0.f, 0.f};
#pragma unroll 8
      for (int r = 0; r < cpc; ++r) {
        const int c = cbase + r;
        const f32x4 wv = *reinterpret_cast<const f32x4*>(&wT[(size_t)c * out + grp * 4]);
        const float vc = v[c];
        acc[0] += wv[0] * vc; acc[1] += wv[1] * vc;
        acc[2] += wv[2] * vc; acc[3] += wv[3] * vc;
      }
      *reinterpret_cast<f32x4*>(&part[ch * out + grp * 4]) = acc;
      __syncthreads();
      if (tid < out) {
        float s = 0.f;
        for (int c2 = 0; c2 < nch; ++c2) s += part[c2 * out + tid];
        u[tid] = s;
      }
    }
    {
      float su = 0.f;
      __syncthreads();
      if (tid < out) su = u[tid] * u[tid];
      su = breduce1024(su, red);
      const float sv2 = 1.f / (sqrtf(su) + 1e-12f);
      if (tid < out) u[tid] *= sv2;
      __syncthreads();
    }
  }
  float sp = 0.f;
  {
    const int G = out >> 2, nch = 1024 / G;
    const int ch = tid / G, grp = tid - ch * G;
    const int cpc = in / nch, cbase = ch * cpc;
    f32x4 acc = {0.f, 0.f, 0.f, 0.f};
#pragma unroll 8
    for (int r = 0; r < cpc; ++r) {
      const int c = cbase + r;
      const f32x4 wv = *reinterpret_cast<const f32x4*>(&wT[(size_t)c * out + grp * 4]);
      const float vc = v[c];
      acc[0] += wv[0] * vc; acc[1] += wv[1] * vc;
      acc[2] += wv[2] * vc; acc[3] += wv[3] * vc;
    }
    *reinterpret_cast<f32x4*>(&part[ch * out + grp * 4]) = acc;
    __syncthreads();
    if (tid < out) {
      float s = 0.f;
      for (int c2 = 0; c2 < nch; ++c2) s += part[c2 * out + tid];
      sp = s * u[tid];
    }
  }
  sp = breduce1024(sp, red);
  const float oscale = (blockIdx.x == 0) ? 1.44269504f : 1.0f;
  const float inv_sigma = (1.f / sp) * oscale;
  const int total = out * in;
  for (int i = tid * 4; i < total; i += 4096) {
    const f32x4 wv = *reinterpret_cast<const f32x4*>(&w[i]);
    u32x2 pw;
    pw[0] = ((unsigned)f2b(wv[1] * inv_sigma) << 16) | f2b(wv[0] * inv_sigma);
    pw[1] = ((unsigned)f2b(wv[3] * inv_sigma) << 16) | f2b(wv[2] * inv_sigma);
    *reinterpret_cast<u32x2*>(&dst[i]) = pw;
  }
}

// ---------------------------------------------------------------- K2: fused QKV GEMM + maxpool
// Yt = xb @ wqkv^T per 128n x 128m tile. mt=0: write Q half to ytq[n][64],
// pool K half -> gt[mp][64]. mt=1,2: pool V cols -> vt[cv][mp] (transposed).
__global__ __launch_bounds__(256) void k_gemm_qkv(
    const unsigned short* __restrict__ xb, const unsigned short* __restrict__ wqkv,
    unsigned short* __restrict__ ytq, unsigned short* __restrict__ gt,
    unsigned short* __restrict__ vt) {
  __shared__ alignas(16) char smem[32768];
  unsigned short* As = (unsigned short*)smem;
  unsigned short* Bs = (unsigned short*)(smem + 16384);
  const int lid = blockIdx.x;
  const int swz = (lid & 7) * 192 + (lid >> 3);
  const int mt = swz % 3, rest = swz / 3;
  const int nt = rest & 31, b = rest >> 5;
  const int n0 = nt * 128, m0 = mt * 128;
  const unsigned short* Ap = xb + (size_t)b * HW_ * C_ + (size_t)n0 * C_;
  const unsigned short* Bp = wqkv + (size_t)m0 * C_;
  const int tid = threadIdx.x, lane = tid & 63, wid = tid >> 6;
  const int wn = (wid >> 1) * 64, wm = (wid & 1) * 64;
  f32x4 acc[4][4] = {};
  for (int k0 = 0; k0 < C_; k0 += 64) {
    __syncthreads();
#pragma unroll
    for (int i = 0; i < 4; ++i) {
      const int r = i * 32 + (tid >> 3);
      const int s = tid & 7;
      const int rw = i * 32 + wid * 8;
      const size_t goff = (size_t)r * C_ + k0 + (size_t)((s ^ (r & 7)) * 8);
      gload_lds16(&Ap[goff], &As[rw * 64]);
      gload_lds16(&Bp[goff], &Bs[rw * 64]);
    }
    __syncthreads();
#pragma unroll
    for (int kk = 0; kk < 2; ++kk) {
      bf16x8 af[4], bfr[4];
#pragma unroll
      for (int i = 0; i < 4; ++i) {
        const int r = wn + i * 16 + (lane & 15);
        const int slot = (kk * 4 + (lane >> 4)) ^ (r & 7);
        af[i] = *reinterpret_cast<const bf16x8*>(&As[r * 64 + slot * 8]);
      }
#pragma unroll
      for (int j = 0; j < 4; ++j) {
        const int r = wm + j * 16 + (lane & 15);
        const int slot = (kk * 4 + (lane >> 4)) ^ (r & 7);
        bfr[j] = *reinterpret_cast<const bf16x8*>(&Bs[r * 64 + slot * 8]);
      }
#pragma unroll
      for (int i = 0; i < 4; ++i)
#pragma unroll
        for (int j = 0; j < 4; ++j) acc[i][j] = mfma16(af[i], bfr[j], acc[i][j]);
    }
  }
  // ---- fused epilogue ----
  unsigned short* eps = (unsigned short*)smem;            // 64 x 136 bf16 (17408B)
  float* pmk = (float*)(smem + 20480);                    // mt0: [32][68] f32 (8704B)
  unsigned short* pmv = (unsigned short*)(smem + 20480);  // mt12: [32][136] bf16 (8704B)
  const int mp0 = nt * 32;
  unsigned short* Yq = ytq + (size_t)b * HW_ * 64;
  unsigned short* Gp = gt + (size_t)b * HWP_ * 64;
  unsigned short* Vp = vt + (size_t)b * CV_ * HWP_;
#pragma unroll
  for (int h = 0; h < 2; ++h) {
    __syncthreads();
    if ((wid >> 1) == h) {
#pragma unroll
      for (int i = 0; i < 4; ++i)
#pragma unroll
        for (int j = 0; j < 4; ++j)
#pragma unroll
          for (int r = 0; r < 4; ++r) {
            const int nl = i * 16 + (lane >> 4) * 4 + r;
            const int ml = wm + j * 16 + (lane & 15);
            eps[nl * 136 + ml] = f2b(acc[i][j][r]);
          }
    }
    __syncthreads();
    if (mt == 0) {
      // Q store: 64 rows x 64 cols -> ytq (dense stride 64)
      {
        const int row = tid >> 2, qc = (tid & 3) * 16;
        *reinterpret_cast<f32x4*>(&Yq[(size_t)(n0 + h * 64 + row) * 64 + qc]) =
            *reinterpret_cast<const f32x4*>(&eps[row * 136 + qc]);
        *reinterpret_cast<f32x4*>(&Yq[(size_t)(n0 + h * 64 + row) * 64 + qc + 8]) =
            *reinterpret_cast<const f32x4*>(&eps[row * 136 + qc + 8]);
      }
      // K pool partial: rows 2j, 2j+1 of this chunk; cols 64..127
      {
        const int j = tid >> 3, mg = tid & 7;
        const bf16x8 a = *reinterpret_cast<const bf16x8*>(&eps[(2 * j) * 136 + 64 + mg * 8]);
        const bf16x8 bb = *reinterpret_cast<const bf16x8*>(&eps[(2 * j + 1) * 136 + 64 + mg * 8]);
        float* pd = &pmk[j * 68 + mg * 8];
#pragma unroll
        for (int e = 0; e < 8; ++e) {
          const float m2 = fmaxf(b2f((unsigned short)a[e]), b2f((unsigned short)bb[e]));
          pd[e] = (h == 0) ? m2 : fmaxf(pd[e], m2);
        }
      }
    } else {
      // V pool partial: all 128 cols
#pragma unroll
      for (int t2 = 0; t2 < 2; ++t2) {
        const int it = tid + t2 * 256;
        const int j = it >> 4, mg = it & 15;
        const bf16x8 a = *reinterpret_cast<const bf16x8*>(&eps[(2 * j) * 136 + mg * 8]);
        const bf16x8 bb = *reinterpret_cast<const bf16x8*>(&eps[(2 * j + 1) * 136 + mg * 8]);
        float m8[8];
#pragma unroll
        for (int e = 0; e < 8; ++e)
          m8[e] = fmaxf(b2f((unsigned short)a[e]), b2f((unsigned short)bb[e]));
        unsigned short* pv = &pmv[j * 136 + mg * 8];
        if (h == 1) {
          const bf16x8 prev = *reinterpret_cast<const bf16x8*>(pv);
#pragma unroll
          for (int e = 0; e < 8; ++e) m8[e] = fmaxf(m8[e], b2f((unsigned short)prev[e]));
        }
        u32x4 w;
        w[0] = pkbf16(m8[0], m8[1]); w[1] = pkbf16(m8[2], m8[3]);
        w[2] = pkbf16(m8[4], m8[5]); w[3] = pkbf16(m8[6], m8[7]);
        *reinterpret_cast<u32x4*>(pv) = w;
      }
    }
  }
  __syncthreads();
  if (mt == 0) {
    // gt write: [mp0+j][ck], 32 x 64
    const int j = tid >> 3, ck0 = (tid & 7) * 8;
    const float* ps = &pmk[j * 68 + ck0];
    u32x4 w;
    w[0] = pkbf16(ps[0], ps[1]); w[1] = pkbf16(ps[2], ps[3]);
    w[2] = pkbf16(ps[4], ps[5]); w[3] = pkbf16(ps[6], ps[7]);
    *reinterpret_cast<u32x4*>(&Gp[(size_t)(mp0 + j) * 64 + ck0]) = w;
  } else {
    // vt write (transposed): [cv0+ml][mp0+j0..j0+15]
    const int cv0 = (mt - 1) * 128;
    const int ml = tid >> 1, j0 = (tid & 1) * 16;
    unsigned w[8];
#pragma unroll
    for (int p = 0; p < 8; ++p) {
      const unsigned lo = pmv[(j0 + 2 * p) * 136 + ml];
      const unsigned hi = pmv[(j0 + 2 * p + 1) * 136 + ml];
      w[p] = lo | (hi << 16);
    }
    unsigned short* dst = &Vp[(size_t)(cv0 + ml) * HWP_ + mp0 + j0];
    *reinterpret_cast<u32x4*>(dst) = *reinterpret_cast<u32x4*>(&w[0]);
    *reinterpret_cast<u32x4*>(dst + 8) = *reinterpret_cast<u32x4*>(&w[4]);
  }
}

// ---------------------------------------------------------------- K4: flash attention, 8 waves x 16q = 128q/block
// R13 single-barrier dbuf pipeline + VALU diet; Q from compact ytq[n][64].
__global__ __launch_bounds__(512, 4) void k_attn(
    const unsigned short* __restrict__ ytq, const unsigned short* __restrict__ gt,
    const unsigned short* __restrict__ vt, unsigned short* __restrict__ oat) {
  __shared__ alignas(16) char smem[59392];
  const int lid = blockIdx.x;                              // 512 blocks
  const int swz = (lid & 7) * 64 + (lid >> 3);
  const int q0 = (swz & 31) * 128, b = swz >> 5;
  const int tid = threadIdx.x, lane = tid & 63, wid = tid >> 6;  // 8 waves
  const int q = lane & 15, g = lane >> 4;
  const unsigned short* Qg = ytq + (size_t)b * HW_ * 64 + (size_t)(q0 + wid * 16) * 64;
  const unsigned short* Gg = gt + (size_t)b * HWP_ * 64;
  const unsigned short* Vg = vt + (size_t)b * CV_ * HWP_;
  unsigned short* P = (unsigned short*)(smem + 49152) + wid * 640;  // 16q x 40sh
  bf16x8 qf[2];
#pragma unroll
  for (int kk = 0; kk < 2; ++kk)
    qf[kk] = *reinterpret_cast<const bf16x8*>(&Qg[(size_t)q * 64 + kk * 32 + g * 8]);
  const int kr = tid >> 3, ks = tid & 7;   // valid when tid<256
  f32x4 kreg, vreg[2];
  if (tid < 256) kreg = *reinterpret_cast<const f32x4*>(&Gg[(size_t)kr * 64 + ks * 8]);
  const unsigned short* vp0;
  const unsigned short* vp1;
  {
    const int i0c = tid, r0 = i0c >> 2, s0 = i0c & 3;
    const int i1c = tid + 512, r1 = i1c >> 2, s1 = i1c & 3;
    vp0 = Vg + (size_t)r0 * HWP_ + s0 * 8;
    vp1 = Vg + (size_t)r1 * HWP_ + s1 * 8;
    vreg[0] = *reinterpret_cast<const f32x4*>(vp0);
    vreg[1] = *reinterpret_cast<const f32x4*>(vp1);
  }
  {
    unsigned short* Kb = (unsigned short*)smem;
    unsigned short* Vb = (unsigned short*)(smem + 8192);
    if (tid < 256)
      *reinterpret_cast<f32x4*>(&Kb[kr * 64 + (ks ^ (kr & 7)) * 8]) = kreg;
    const int i0c = tid, r0 = i0c >> 2, s0 = i0c & 3;
    const int i1c = tid + 512, r1 = i1c >> 2, s1 = i1c & 3;
    *reinterpret_cast<f32x4*>(&Vb[r0 * 40 + s0 * 8]) = vreg[0];
    *reinterpret_cast<f32x4*>(&Vb[r1 * 40 + s1 * 8]) = vreg[1];
  }
  const unsigned short* kp = Gg + (size_t)(32 + kr) * 64 + ks * 8;
  if (tid < 256) kreg = *reinterpret_cast<const f32x4*>(kp);
  kp += 2048;
  vp0 += 32; vp1 += 32;
  vreg[0] = *reinterpret_cast<const f32x4*>(vp0);
  vreg[1] = *reinterpret_cast<const f32x4*>(vp1);
  vp0 += 32; vp1 += 32;
  __syncthreads();
  f32x4 oacc[16] = {};
  float m_run = -1e30f, l_part = 0.f;
#pragma unroll 2
  for (int it = 0; it < 32; ++it) {
    const int cur = it & 1;
    unsigned short* Kc = (unsigned short*)(smem + cur * 4096);
    unsigned short* Vc = (unsigned short*)(smem + 8192 + cur * 20480);
    if (it < 31) {
      unsigned short* Kn = (unsigned short*)(smem + (cur ^ 1) * 4096);
      unsigned short* Vn = (unsigned short*)(smem + 8192 + (cur ^ 1) * 20480);
      if (tid < 256)
        *reinterpret_cast<f32x4*>(&Kn[kr * 64 + (ks ^ (kr & 7)) * 8]) = kreg;
      const int i0c = tid, r0 = i0c >> 2, s0 = i0c & 3;
      const int i1c = tid + 512, r1 = i1c >> 2, s1 = i1c & 3;
      *reinterpret_cast<f32x4*>(&Vn[r0 * 40 + s0 * 8]) = vreg[0];
      *reinterpret_cast<f32x4*>(&Vn[r1 * 40 + s1 * 8]) = vreg[1];
    }
    if (it < 30) {
      if (tid < 256) kreg = *reinterpret_cast<const f32x4*>(kp);
      kp += 2048;
      vreg[0] = *reinterpret_cast<const f32x4*>(vp0);
      vreg[1] = *reinterpret_cast<const f32x4*>(vp1);
      vp0 += 32; vp1 += 32;
    }
    f32x4 sacc[2] = {};
#pragma unroll
    for (int kk = 0; kk < 2; ++kk) {
      bf16x8 kf[2];
#pragma unroll
      for (int i = 0; i < 2; ++i) {
        const int row = i * 16 + q;
        const int sl = (kk * 4 + g) ^ (row & 7);
        kf[i] = *reinterpret_cast<const bf16x8*>(&Kc[row * 64 + sl * 8]);
      }
#pragma unroll
      for (int i = 0; i < 2; ++i) sacc[i] = mfma16(kf[i], qf[kk], sacc[i]);
    }
    float tmax = fmaxf(fmaxf(fmaxf(sacc[0][0], sacc[0][1]), fmaxf(sacc[0][2], sacc[0][3])),
                       fmaxf(fmaxf(sacc[1][0], sacc[1][1]), fmaxf(sacc[1][2], sacc[1][3])));
    tmax = fmaxf(tmax, __shfl_xor(tmax, 16));
    tmax = fmaxf(tmax, __shfl_xor(tmax, 32));
    if (__any(tmax > m_run + 11.0f)) {
      const float mnew = fmaxf(m_run, tmax);
      const float alpha = exp2f(m_run - mnew);
      m_run = mnew;
      l_part *= alpha;
      float al[4];
#pragma unroll
      for (int r = 0; r < 4; ++r) al[r] = __shfl(alpha, g * 4 + r);
#pragma unroll
      for (int j = 0; j < 16; ++j) {
        oacc[j][0] *= al[0]; oacc[j][1] *= al[1];
        oacc[j][2] *= al[2]; oacc[j][3] *= al[3];
      }
    }
#pragma unroll
    for (int i = 0; i < 2; ++i) {
      const float p0 = exp2f(sacc[i][0] - m_run);
      const float p1 = exp2f(sacc[i][1] - m_run);
      const float p2 = exp2f(sacc[i][2] - m_run);
      const float p3 = exp2f(sacc[i][3] - m_run);
      l_part += (p0 + p1) + (p2 + p3);
      u32x2 pw;
      pw[0] = pkbf16(p0, p1);
      pw[1] = pkbf16(p2, p3);
      *reinterpret_cast<u32x2*>(&P[q * 40 + i * 16 + g * 4]) = pw;
    }
    __builtin_amdgcn_s_setprio(1);
    const bf16x8 pa = *reinterpret_cast<const bf16x8*>(&P[q * 40 + g * 8]);
#pragma unroll
    for (int j = 0; j < 16; ++j) {
      const int row = j * 16 + q;
      const bf16x8 vf = *reinterpret_cast<const bf16x8*>(&Vc[row * 40 + g * 8]);
      oacc[j] = mfma16(pa, vf, oacc[j]);
    }
    __builtin_amdgcn_s_setprio(0);
    __syncthreads();
  }
  float lsum = l_part;
  lsum += __shfl_xor(lsum, 16);
  lsum += __shfl_xor(lsum, 32);
  float linv[4];
  {
    const float myinv = 1.f / lsum;
#pragma unroll
    for (int r = 0; r < 4; ++r) linv[r] = __shfl(myinv, g * 4 + r);
  }
  unsigned short* eps = (unsigned short*)smem;
  unsigned short* O = oat + (size_t)b * HW_ * CV_ + (size_t)q0 * CV_;
#pragma unroll
  for (int ch = 0; ch < 2; ++ch) {
    __syncthreads();
    if ((wid >> 2) == ch) {
#pragma unroll
      for (int j = 0; j < 16; ++j)
#pragma unroll
        for (int r = 0; r < 4; ++r) {
          const int row = (wid & 3) * 16 + g * 4 + r;
          const int cv = j * 16 + q;
          eps[row * 264 + cv] = f2b(oacc[j][r] * linv[r]);
        }
    }
    __syncthreads();
#pragma unroll
    for (int t = 0; t < 4; ++t) {
      const int row = t * 16 + (tid >> 5);
      const int cv8 = (tid & 31) * 8;
      *reinterpret_cast<f32x4*>(&O[(size_t)(ch * 64 + row) * CV_ + cv8]) =
          *reinterpret_cast<const f32x4*>(&eps[row * 264 + cv8]);
    }
  }
}

// ---------------------------------------------------------------- K5: out[b][co][n] = gamma * wo@Oatt^T + x
__global__ __launch_bounds__(256) void k_gemm_out(
    const unsigned short* __restrict__ oat, const unsigned short* __restrict__ wob,
    const float* __restrict__ x, const float* __restrict__ gamma,
    float* __restrict__ out) {
  __shared__ alignas(16) char smem[32768];
  unsigned short* As = (unsigned short*)smem;
  unsigned short* Bs = (unsigned short*)(smem + 16384);
  const int lid = blockIdx.x;
  const int swz = (lid & 7) * 256 + (lid >> 3);
  const int ct = swz & 3, nt = (swz >> 2) & 31, b = swz >> 7;
  const int n0 = nt * 128, co0 = ct * 128;
  const unsigned short* Ap = wob + (size_t)co0 * CV_;
  const unsigned short* Bp = oat + (size_t)b * HW_ * CV_ + (size_t)n0 * CV_;
  const int tid = threadIdx.x, lane = tid & 63, wid = tid >> 6;
  const int wc = (wid >> 1) * 64, wn = (wid & 1) * 64;
  f32x4 acc[4][4] = {};
  for (int k0 = 0; k0 < CV_; k0 += 64) {
    __syncthreads();
#pragma unroll
    for (int i = 0; i < 4; ++i) {
      const int r = i * 32 + (tid >> 3);
      const int s = tid & 7;
      const int rw = i * 32 + wid * 8;
      const size_t goff = (size_t)r * CV_ + k0 + (size_t)((s ^ (r & 7)) * 8);
      gload_lds16(&Ap[goff], &As[rw * 64]);
      gload_lds16(&Bp[goff], &Bs[rw * 64]);
    }
    __syncthreads();
#pragma unroll
    for (int kk = 0; kk < 2; ++kk) {
      bf16x8 af[4], bfr[4];
#pragma unroll
      for (int i = 0; i < 4; ++i) {
        const int r = wc + i * 16 + (lane & 15);
        const int slot = (kk * 4 + (lane >> 4)) ^ (r & 7);
        af[i] = *reinterpret_cast<const bf16x8*>(&As[r * 64 + slot * 8]);
      }
#pragma unroll
      for (int j = 0; j < 4; ++j) {
        const int r = wn + j * 16 + (lane & 15);
        const int slot = (kk * 4 + (lane >> 4)) ^ (r & 7);
        bfr[j] = *reinterpret_cast<const bf16x8*>(&Bs[r * 64 + slot * 8]);
      }
#pragma unroll
      for (int i = 0; i < 4; ++i)
#pragma unroll
        for (int j = 0; j < 4; ++j) acc[i][j] = mfma16(af[i], bfr[j], acc[i][j]);
    }
  }
  float* eps = (float*)smem;
  const float g = gamma[0];
  const size_t base = (size_t)b * C_ * HW_;
#pragma unroll
  for (int h = 0; h < 4; ++h) {
    __syncthreads();
    if ((wid >> 1) == (h >> 1)) {
#pragma unroll
      for (int ii = 0; ii < 2; ++ii) {
        const int i = (h & 1) * 2 + ii;
#pragma unroll
        for (int j = 0; j < 4; ++j)
#pragma unroll
          for (int r = 0; r < 4; ++r) {
            const int col2 = ii * 16 + (lane >> 4) * 4 + r;
            const int nl = wn + j * 16 + (lane & 15);
            eps[col2 * 132 + nl] = acc[i][j][r];
          }
      }
    }
    __syncthreads();
#pragma unroll
    for (int t = 0; t < 4; ++t) {
      const int row = t * 8 + (tid >> 5);
      const int col = (tid & 31) * 4;
      const size_t goff = base + (size_t)(co0 + h * 32 + row) * HW_ + n0 + col;
      const f32x4 xv = *reinterpret_cast<const f32x4*>(&x[goff]);
      const f32x4 av = *reinterpret_cast<const f32x4*>(&eps[row * 132 + col]);
      f32x4 ov;
      ov[0] = g * av[0] + xv[0];
      ov[1] = g * av[1] + xv[1];
      ov[2] = g * av[2] + xv[2];
      ov[3] = g * av[3] + xv[3];
      *reinterpret_cast<f32x4*>(&out[goff]) = ov;
    }
  }
}

// ---------------------------------------------------------------- launcher
extern "C" void kernel_launch(void* const* d_in, const int* in_sizes, int n_in,
                              void* d_out, int out_size, void* d_ws, size_t ws_size,
                              hipStream_t stream) {
  (void)in_sizes; (void)n_in; (void)out_size; (void)ws_size;
  const float* x     = (const float*)d_in[0];
  const float* Wq    = (const float*)d_in[1];
  const float* Wk    = (const float*)d_in[2];
  const float* Wv    = (const float*)d_in[3];
  const float* Wo    = (const float*)d_in[4];
  const float* gamma = (const float*)d_in[5];
  float* out = (float*)d_out;
  char* ws = (char*)d_ws;

  unsigned short* wqkv = (unsigned short*)(ws);                 // 384*512*2
  unsigned short* wob  = (unsigned short*)(ws + 393216);        // 512*256*2
  unsigned short* xb   = (unsigned short*)(ws + 655360);        // 64MB
  unsigned short* ytq  = (unsigned short*)(ws + 67764224);      // 8MB (Q only, [n][64])
  unsigned short* gt   = (unsigned short*)(ws + 118095872);     // 2MB
  unsigned short* vt   = (unsigned short*)(ws + 120193024);     // 8MB
  unsigned short* oat  = xb;   // alias: xb dead after k_gemm_qkv
  float* wt = (float*)ytq;     // alias: wT only live during specnorm (ytq written later)

  k_transpose<<<dim3(64, 8, 16), 256, 0, stream>>>(x, xb);
  k_wtrans<<<dim3(8, 8, 4), 256, 0, stream>>>(Wq, Wk, Wv, Wo, wt);
  k_specnorm<<<4, 1024, 0, stream>>>(Wq, Wk, Wv, Wo, wt, wqkv, wob);
  k_gemm_qkv<<<1536, 256, 0, stream>>>(xb, wqkv, ytq, gt, vt);
  k_attn<<<512, 512, 0, stream>>>(ytq, gt, vt, oat);
  k_gemm_out<<<2048, 256, 0, stream>>>(oat, wob, x, gamma, out);
}